// Round 2
// baseline (955.830 us; speedup 1.0000x reference)
//
#include <hip/hip_runtime.h>

// ---------------------------------------------------------------------------
// FoldIteration (AlphaFold IPA + transition + rigid update).
// N=768, C=384, C2=128, H=12, PQK=4, PV=8, CQK=16, CV=16. Out: [768, 396].
// Dtype-dual: probes input dtype (f32 vs bf16) on device, converts all small
// inputs to canonical bf16 in ws; inputs_2d consumers + d_out writers branch.
// ---------------------------------------------------------------------------

typedef unsigned short bfu;
typedef unsigned int u32;

__device__ __forceinline__ float bf2f(bfu u) {
    return __uint_as_float(((u32)u) << 16);
}
__device__ __forceinline__ bfu f2bf(float f) {
    u32 x = __float_as_uint(f);
    u32 r = x + 0x7fffu + ((x >> 16) & 1u);
    return (bfu)(r >> 16);
}
__device__ __forceinline__ float bflo(u32 u) { return __uint_as_float(u << 16); }
__device__ __forceinline__ float bfhi(u32 u) { return __uint_as_float(u & 0xffff0000u); }

// ---- workspace layout (bytes) ----
#define OFF_PL      0u               // pl bf16 [768][1152]  (qs|ks|vs|qp|kp|vp)
#define OFF_FQ      1769472u         // fq f32 [768][12][32]
#define OFF_GK      2949120u         // gk f32 [768][12][32]
#define OFF_VST     4128768u         // vsT bf16 [192][768]
#define OFF_VGT     4423680u         // vgT bf16 [288][768]
#define OFF_LOGITS  4866048u         // logits f32 [12][768][768]
#define OFF_FINAL   33177600u        // final bf16 [768][2112]
#define OFF_ATTNOUT 36421632u        // bf16 [768][384]
#define OFF_ACT     37011456u        // bf16 [768][384]
#define OFF_X1      37601280u        // bf16 [768][384]
#define OFF_X2      38191104u        // bf16 [768][384]  (reused as act2 after gemm3)
#define OFF_WCAT    38780928u        // bf16 [384][1152]
#define OFF_BCAT    39665664u        // bf16 [1152]
#define OFF_CONV    39667968u        // bf16 canonical copies of 30 small inputs
#define OFF_FLAG    43684288u        // u32 flags[2]: [0]=act-class f32, [1]=out f32

#define CONV_TOTAL 2008158

struct P30 { const void* p[30]; };

// per-tensor end offsets (elements) in conversion order (= d_in order minus inputs_2d)
static __device__ const int kEnd[30] = {
    294912, 295680, 302592, 304896, 360192, 360336, 415632, 415776,
    526368, 526656, 600384, 674112, 747840, 747852, 749388, 749400,
    1560408, 1560792, 1561176, 1561560, 1709016, 1709400, 1856856, 1857240,
    2004696, 2005080, 2005464, 2005848, 2008152, 2008158
};

// ---------------------------------------------------------------------------
// k_convert: detect dtypes via known all-ones tensors (mask = conv idx 1,
// ln1_s = conv idx 18): f32 1.0f -> first u32 == 0x3F800000; bf16 -> 0x3F803F80.
// Convert every small input to bf16 at conv[].
// ---------------------------------------------------------------------------
__global__ __launch_bounds__(256) void k_convert(P30 ps, bfu* __restrict__ conv,
                                                 u32* __restrict__ flags) {
    u32 pm = *(const u32*)ps.p[1];    // mask[0..1]   (activation class)
    u32 pp = *(const u32*)ps.p[18];   // ln1_s[0..1]  (param class)
    u32 fA = (pm == 0x3F800000u) ? 1u : 0u;
    u32 fB = (pp == 0x3F800000u) ? 1u : 0u;
    int idx = blockIdx.x * 256 + threadIdx.x;
    if (idx == 0) { flags[0] = fA; flags[1] = fA & fB; }
    if (idx >= CONV_TOTAL) return;
    int t = 0;
    while (idx >= kEnd[t]) ++t;
    int local = idx - (t ? kEnd[t - 1] : 0);
    u32 f = (t < 4) ? fA : fB;        // in1d, mask, rot, trans = activation class
    float v = f ? ((const float*)ps.p[t])[local]
                : bf2f(((const bfu*)ps.p[t])[local]);
    conv[idx] = f2bf(v);
}

// ---------------------------------------------------------------------------
// Concat the 6 projection weight matrices into wcat[384][1152] (+ bias).
// Columns: [qs 0:192 | ks 192:384 | vs 384:576 | qp 576:720 | kp 720:864 | vp 864:1152]
// ---------------------------------------------------------------------------
__global__ __launch_bounds__(256) void k_concat(
    const bfu* __restrict__ wqs, const bfu* __restrict__ wks, const bfu* __restrict__ wvs,
    const bfu* __restrict__ wqp, const bfu* __restrict__ bqp,
    const bfu* __restrict__ wkp, const bfu* __restrict__ bkp,
    const bfu* __restrict__ wvp, const bfu* __restrict__ bvp,
    bfu* __restrict__ wcat, bfu* __restrict__ bcat) {
    int idx = blockIdx.x * 256 + threadIdx.x;
    if (idx < 384 * 1152) {
        int row = idx / 1152, col = idx - row * 1152;
        bfu v;
        if      (col < 192) v = wqs[row * 192 + col];
        else if (col < 384) v = wks[row * 192 + col - 192];
        else if (col < 576) v = wvs[row * 192 + col - 384];
        else if (col < 720) v = wqp[row * 144 + col - 576];
        else if (col < 864) v = wkp[row * 144 + col - 720];
        else                v = wvp[row * 288 + col - 864];
        wcat[idx] = v;
    } else if (idx < 384 * 1152 + 1152) {
        int col = idx - 384 * 1152;
        bfu v;
        if      (col < 576) v = 0;
        else if (col < 720) v = bqp[col - 576];
        else if (col < 864) v = bkp[col - 720];
        else                v = bvp[col - 864];
        bcat[col] = v;
    }
}

// ---------------------------------------------------------------------------
// Generic tiled GEMM: out[768][M] = A[768][K] @ W[K][M] + bias, optional relu.
// ---------------------------------------------------------------------------
template <int RELU>
__global__ __launch_bounds__(256) void k_gemm(
    const bfu* __restrict__ A, const bfu* __restrict__ W, const bfu* __restrict__ bias,
    bfu* __restrict__ out, int K, int M) {
    __shared__ float As[32][34];
    __shared__ float Ws[32][34];
    int t = threadIdx.x;
    int c0 = blockIdx.x * 32, r0 = blockIdx.y * 32;
    int tr = t >> 4, tc = t & 15;
    float a00 = 0, a01 = 0, a10 = 0, a11 = 0;
    int nch = K >> 5;
    for (int ch = 0; ch < nch; ++ch) {
        int kc = ch * 32;
#pragma unroll
        for (int i = 0; i < 4; ++i) {
            int idx = t + i * 256;
            int r = idx >> 5, c = idx & 31;
            As[c][r] = bf2f(A[(size_t)(r0 + r) * K + kc + c]);
        }
#pragma unroll
        for (int i = 0; i < 4; ++i) {
            int idx = t + i * 256;
            int r = idx >> 5, c = idx & 31;
            Ws[r][c] = bf2f(W[(size_t)(kc + r) * M + c0 + c]);
        }
        __syncthreads();
#pragma unroll
        for (int kk = 0; kk < 32; ++kk) {
            float x0 = As[kk][2 * tr], x1 = As[kk][2 * tr + 1];
            float w0 = Ws[kk][2 * tc], w1 = Ws[kk][2 * tc + 1];
            a00 += x0 * w0; a01 += x0 * w1;
            a10 += x1 * w0; a11 += x1 * w1;
        }
        __syncthreads();
    }
    float b0 = bf2f(bias[c0 + 2 * tc]), b1 = bf2f(bias[c0 + 2 * tc + 1]);
    float v00 = a00 + b0, v01 = a01 + b1, v10 = a10 + b0, v11 = a11 + b1;
    if (RELU) {
        v00 = fmaxf(v00, 0.f); v01 = fmaxf(v01, 0.f);
        v10 = fmaxf(v10, 0.f); v11 = fmaxf(v11, 0.f);
    }
    u32 p0 = (u32)f2bf(v00) | ((u32)f2bf(v01) << 16);
    u32 p1 = (u32)f2bf(v10) | ((u32)f2bf(v11) << 16);
    *(u32*)&out[(size_t)(r0 + 2 * tr) * M + c0 + 2 * tc] = p0;
    *(u32*)&out[(size_t)(r0 + 2 * tr + 1) * M + c0 + 2 * tc] = p1;
}

// ---------------------------------------------------------------------------
// Per-residue rigid transforms + augmented QK feature vectors + transposed V.
// fq[n][h][32] = [ 0.25*qs(16) | qg(12) | -0.5*pw*qn | 1 | b2d | 0 ]
// gk[n][h][32] = [ ks(16)      | pw*kg(12) | 1 | -0.5*pw*kn | 1 | 0 ]
// ---------------------------------------------------------------------------
__global__ __launch_bounds__(64) void k_rigid(
    const bfu* __restrict__ pl, const bfu* __restrict__ rot, const bfu* __restrict__ trans,
    const bfu* __restrict__ tpw, const bfu* __restrict__ b2d,
    float* __restrict__ fq, float* __restrict__ gk,
    bfu* __restrict__ vsT, bfu* __restrict__ vgT) {
    int n = blockIdx.x, t = threadIdx.x;
    __shared__ float pls[1152];
    __shared__ float qgs[144], kgs[144];
    __shared__ float rs[9], ts3[3], pws[12], qns[12], kns[12];
    for (int i = t; i < 1152; i += 64) pls[i] = bf2f(pl[(size_t)n * 1152 + i]);
    if (t < 9)  rs[t] = bf2f(rot[n * 9 + t]);
    if (t < 3)  ts3[t] = bf2f(trans[n * 3 + t]);
    if (t < 12) pws[t] = 0.23570226039551584f * log1pf(expf(bf2f(tpw[t])));
    __syncthreads();
    for (int idx = t; idx < 144; idx += 64) {
        int h = idx / 12, r = idx - h * 12, p = r / 3, i = r - p * 3;
        float q0 = pls[576 + h * 12 + p], q1 = pls[576 + h * 12 + 4 + p], q2 = pls[576 + h * 12 + 8 + p];
        qgs[idx] = rs[i * 3 + 0] * q0 + rs[i * 3 + 1] * q1 + rs[i * 3 + 2] * q2 + ts3[i];
        float k0 = pls[720 + h * 12 + p], k1 = pls[720 + h * 12 + 4 + p], k2 = pls[720 + h * 12 + 8 + p];
        kgs[idx] = rs[i * 3 + 0] * k0 + rs[i * 3 + 1] * k1 + rs[i * 3 + 2] * k2 + ts3[i];
    }
    for (int idx = t; idx < 288; idx += 64) {
        int h = idx / 24, r = idx - h * 24, p = r / 3, i = r - p * 3;
        float v0 = pls[864 + h * 24 + p], v1 = pls[864 + h * 24 + 8 + p], v2 = pls[864 + h * 24 + 16 + p];
        float v = rs[i * 3 + 0] * v0 + rs[i * 3 + 1] * v1 + rs[i * 3 + 2] * v2 + ts3[i];
        vgT[(size_t)idx * 768 + n] = f2bf(v);
    }
    __syncthreads();
    if (t < 12) {
        float s = 0;
        for (int j = 0; j < 12; ++j) s += qgs[t * 12 + j] * qgs[t * 12 + j];
        qns[t] = s;
        s = 0;
        for (int j = 0; j < 12; ++j) s += kgs[t * 12 + j] * kgs[t * 12 + j];
        kns[t] = s;
    }
    __syncthreads();
    for (int idx = t; idx < 12 * 32; idx += 64) {
        int h = idx >> 5, j = idx & 31;
        float fv, gv;
        if (j < 16)      { fv = 0.25f * pls[h * 16 + j];      gv = pls[192 + h * 16 + j]; }
        else if (j < 28) { fv = qgs[h * 12 + j - 16];         gv = pws[h] * kgs[h * 12 + j - 16]; }
        else if (j == 28){ fv = -0.5f * pws[h] * qns[h];      gv = 1.0f; }
        else if (j == 29){ fv = 1.0f;                          gv = -0.5f * pws[h] * kns[h]; }
        else if (j == 30){ fv = bf2f(b2d[h]);                  gv = 1.0f; }
        else             { fv = 0.0f;                          gv = 0.0f; }
        fq[((size_t)n * 12 + h) * 32 + j] = fv;
        gk[((size_t)n * 12 + h) * 32 + j] = gv;
    }
    for (int idx = t; idx < 192; idx += 64)
        vsT[(size_t)idx * 768 + n] = f2bf(pls[384 + idx]);
}

// ---------------------------------------------------------------------------
// K2a: logits[h][q][k] = sum_c fq[q][h][c] * gk[k][h][c]
// ---------------------------------------------------------------------------
__global__ __launch_bounds__(256) void k2a(
    const float* __restrict__ fq, const float* __restrict__ gk, float* __restrict__ logits) {
    int t = threadIdx.x;
    int k0 = blockIdx.x * 64, q0 = blockIdx.y * 64, h = blockIdx.z;
    __shared__ float Fs[64][33], Gs[64][33];
#pragma unroll
    for (int i = 0; i < 8; ++i) {
        int idx = t + i * 256;
        int r = idx >> 5, c = idx & 31;
        Fs[r][c] = fq[((size_t)(q0 + r) * 12 + h) * 32 + c];
        Gs[r][c] = gk[((size_t)(k0 + r) * 12 + h) * 32 + c];
    }
    __syncthreads();
    int tq = t >> 4, tk = t & 15;
    float acc[4][4] = {};
#pragma unroll
    for (int kk = 0; kk < 32; ++kk) {
        float f0 = Fs[tq * 4 + 0][kk], f1 = Fs[tq * 4 + 1][kk];
        float f2 = Fs[tq * 4 + 2][kk], f3 = Fs[tq * 4 + 3][kk];
        float g0 = Gs[tk * 4 + 0][kk], g1 = Gs[tk * 4 + 1][kk];
        float g2 = Gs[tk * 4 + 2][kk], g3 = Gs[tk * 4 + 3][kk];
        acc[0][0] += f0 * g0; acc[0][1] += f0 * g1; acc[0][2] += f0 * g2; acc[0][3] += f0 * g3;
        acc[1][0] += f1 * g0; acc[1][1] += f1 * g1; acc[1][2] += f1 * g2; acc[1][3] += f1 * g3;
        acc[2][0] += f2 * g0; acc[2][1] += f2 * g1; acc[2][2] += f2 * g2; acc[2][3] += f2 * g3;
        acc[3][0] += f3 * g0; acc[3][1] += f3 * g1; acc[3][2] += f3 * g2; acc[3][3] += f3 * g3;
    }
#pragma unroll
    for (int i = 0; i < 4; ++i) {
        float4 v = make_float4(acc[i][0], acc[i][1], acc[i][2], acc[i][3]);
        *(float4*)&logits[((size_t)h * 768 + q0 + tq * 4 + i) * 768 + k0 + tk * 4] = v;
    }
}

// ---------------------------------------------------------------------------
// K2b: stream inputs_2d (dtype-branched), add 2d proj + mask, scale sqrt(1/3).
// ---------------------------------------------------------------------------
__global__ __launch_bounds__(256) void k2b(
    const void* __restrict__ in2dv, const bfu* __restrict__ w2d,
    const bfu* __restrict__ mask, float* __restrict__ logits,
    const u32* __restrict__ flags) {
    int t = threadIdx.x;
    int q = blockIdx.y, k = blockIdx.x * 256 + t;
    bool f32m = flags[0] != 0u;
    __shared__ __align__(16) float w2ds[12 * 128];   // [h][c]
    for (int i = t; i < 1536; i += 256) {
        int cc = i / 12, hh2 = i - cc * 12;
        w2ds[hh2 * 128 + cc] = bf2f(w2d[i]);
    }
    __syncthreads();
    float acc[12] = {};
    size_t base = ((size_t)q * 768 + k) * 128;
    if (f32m) {
        const float4* p = (const float4*)((const float*)in2dv + base);
#pragma unroll 8
        for (int cb = 0; cb < 32; ++cb) {
            float4 u = p[cb];
#pragma unroll
            for (int h = 0; h < 12; ++h) {
                float4 w = *(const float4*)&w2ds[h * 128 + cb * 4];
                acc[h] += u.x * w.x + u.y * w.y + u.z * w.z + u.w * w.w;
            }
        }
    } else {
        const uint2* p = (const uint2*)((const bfu*)in2dv + base);
#pragma unroll 8
        for (int cb = 0; cb < 32; ++cb) {
            uint2 u = p[cb];
            float f0 = bflo(u.x), f1 = bfhi(u.x), f2 = bflo(u.y), f3 = bfhi(u.y);
#pragma unroll
            for (int h = 0; h < 12; ++h) {
                float4 w = *(const float4*)&w2ds[h * 128 + cb * 4];
                acc[h] += f0 * w.x + f1 * w.y + f2 * w.z + f3 * w.w;
            }
        }
    }
    float mq = bf2f(mask[q]), mk = bf2f(mask[k]);
    float mterm = 100000.0f * (1.0f - mq * mk);
#pragma unroll
    for (int h = 0; h < 12; ++h) {
        size_t idx = ((size_t)h * 768 + q) * 768 + k;
        logits[idx] = (logits[idx] + acc[h] - mterm) * 0.5773502691896258f;
    }
}

// ---------------------------------------------------------------------------
// K3: per-query block: softmax, res_2d (LDS-tiled in2d), res_scalar, rp_g,
// rigid-inverse + norms, assemble final[q][2112] bf16.
// ---------------------------------------------------------------------------
__global__ __launch_bounds__(256) void k3(
    const float* __restrict__ logits, const void* __restrict__ in2dv,
    const bfu* __restrict__ vsT, const bfu* __restrict__ vgT,
    const bfu* __restrict__ rot, const bfu* __restrict__ trans,
    bfu* __restrict__ finalb, const u32* __restrict__ flags) {
    int q = blockIdx.x, t = threadIdx.x;
    bool f32m = flags[0] != 0u;
    __shared__ __align__(16) float attT[12 * 776];        // [h][k], stride 776
    __shared__ __align__(16) bfu tile[64 * 128];          // in2d chunk [k][c]
    __shared__ float rpg[288];
    __shared__ float rots[9], trs[3];

    for (int h = 0; h < 12; ++h)
        for (int k = t; k < 768; k += 256)
            attT[h * 776 + k] = logits[((size_t)h * 768 + q) * 768 + k];
    __syncthreads();

    if (t < 192) {
        int h = t >> 4, g = t & 15;
        float m = -1e30f;
        for (int i = 0; i < 48; ++i) m = fmaxf(m, attT[h * 776 + g + i * 16]);
#pragma unroll
        for (int off = 1; off < 16; off <<= 1) m = fmaxf(m, __shfl_xor(m, off));
        float s = 0.f;
        for (int i = 0; i < 48; ++i) {
            float v = __expf(attT[h * 776 + g + i * 16] - m);
            attT[h * 776 + g + i * 16] = v;
            s += v;
        }
#pragma unroll
        for (int off = 1; off < 16; off <<= 1) s += __shfl_xor(s, off);
        float rinv = 1.0f / s;
        for (int i = 0; i < 48; ++i) attT[h * 776 + g + i * 16] *= rinv;
    }
    if (t >= 192 && t < 201) rots[t - 192] = bf2f(rot[q * 9 + t - 192]);
    if (t >= 201 && t < 204) trs[t - 201] = bf2f(trans[q * 3 + t - 201]);
    __syncthreads();

    int cp = t & 63, h0 = t >> 6;
    float p00 = 0, p01 = 0, p10 = 0, p11 = 0, p20 = 0, p21 = 0;
    for (int ch = 0; ch < 12; ++ch) {
#pragma unroll
        for (int i = 0; i < 4; ++i) {
            int idx = t + i * 256;
            int r = idx >> 4, g = idx & 15;
            if (f32m) {
                const float* src = (const float*)in2dv +
                    ((size_t)(q * 768 + ch * 64 + r)) * 128 + g * 8;
                float4 a = *(const float4*)src;
                float4 b = *(const float4*)(src + 4);
                uint4 w;
                w.x = (u32)f2bf(a.x) | ((u32)f2bf(a.y) << 16);
                w.y = (u32)f2bf(a.z) | ((u32)f2bf(a.w) << 16);
                w.z = (u32)f2bf(b.x) | ((u32)f2bf(b.y) << 16);
                w.w = (u32)f2bf(b.z) | ((u32)f2bf(b.w) << 16);
                ((uint4*)tile)[idx] = w;
            } else {
                ((uint4*)tile)[idx] = *(const uint4*)((const bfu*)in2dv +
                    ((size_t)(q * 768 + ch * 64 + r)) * 128 + g * 8);
            }
        }
        __syncthreads();
        const u32* tp = (const u32*)tile;
        const float4* a0p = (const float4*)&attT[(h0 + 0) * 776 + ch * 64];
        const float4* a1p = (const float4*)&attT[(h0 + 4) * 776 + ch * 64];
        const float4* a2p = (const float4*)&attT[(h0 + 8) * 776 + ch * 64];
#pragma unroll 4
        for (int k4 = 0; k4 < 16; ++k4) {
            float4 a0 = a0p[k4], a1 = a1p[k4], a2 = a2p[k4];
            float a0v[4] = {a0.x, a0.y, a0.z, a0.w};
            float a1v[4] = {a1.x, a1.y, a1.z, a1.w};
            float a2v[4] = {a2.x, a2.y, a2.z, a2.w};
#pragma unroll
            for (int u = 0; u < 4; ++u) {
                u32 uu = tp[(k4 * 4 + u) * 64 + cp];
                float lo = bflo(uu), hi = bfhi(uu);
                p00 += a0v[u] * lo; p01 += a0v[u] * hi;
                p10 += a1v[u] * lo; p11 += a1v[u] * hi;
                p20 += a2v[u] * lo; p21 += a2v[u] * hi;
            }
        }
        __syncthreads();
    }
    {
        bfu* fb = finalb + (size_t)q * 2112 + 576;
        *(u32*)&fb[(h0 + 0) * 128 + 2 * cp] = (u32)f2bf(p00) | ((u32)f2bf(p01) << 16);
        *(u32*)&fb[(h0 + 4) * 128 + 2 * cp] = (u32)f2bf(p10) | ((u32)f2bf(p11) << 16);
        *(u32*)&fb[(h0 + 8) * 128 + 2 * cp] = (u32)f2bf(p20) | ((u32)f2bf(p21) << 16);
    }

    if (t < 120) {
        int h = t / 10, oi = t - h * 10;
        const bfu* rp[4];
#pragma unroll
        for (int j = 0; j < 4; ++j) {
            int o = oi * 4 + j;
            rp[j] = (o < 16) ? (vsT + (size_t)(h * 16 + o) * 768)
                             : (vgT + (size_t)(h * 24 + o - 16) * 768);
        }
        float acc[4] = {};
        for (int kb = 0; kb < 96; ++kb) {
            int k8 = kb * 8;
            float4 aL = *(const float4*)&attT[h * 776 + k8];
            float4 aH = *(const float4*)&attT[h * 776 + k8 + 4];
#pragma unroll
            for (int j = 0; j < 4; ++j) {
                uint4 u = *(const uint4*)(rp[j] + k8);
                acc[j] += aL.x * bflo(u.x) + aL.y * bfhi(u.x)
                        + aL.z * bflo(u.y) + aL.w * bfhi(u.y)
                        + aH.x * bflo(u.z) + aH.y * bfhi(u.z)
                        + aH.z * bflo(u.w) + aH.w * bfhi(u.w);
            }
        }
#pragma unroll
        for (int j = 0; j < 4; ++j) {
            int o = oi * 4 + j;
            if (o < 16) finalb[(size_t)q * 2112 + h * 16 + o] = f2bf(acc[j]);
            else rpg[h * 24 + o - 16] = acc[j];
        }
    }
    __syncthreads();

    if (t < 96) {
        int h = t >> 3, p = t & 7;
        float v0 = rpg[h * 24 + p * 3 + 0] - trs[0];
        float v1 = rpg[h * 24 + p * 3 + 1] - trs[1];
        float v2 = rpg[h * 24 + p * 3 + 2] - trs[2];
        float r0 = rots[0] * v0 + rots[3] * v1 + rots[6] * v2;
        float r1 = rots[1] * v0 + rots[4] * v1 + rots[7] * v2;
        float r2 = rots[2] * v0 + rots[5] * v1 + rots[8] * v2;
        float nn = sqrtf(fmaxf(r0 * r0 + r1 * r1 + r2 * r2, 1e-16f));
        size_t fb = (size_t)q * 2112;
        finalb[fb + 192 + h * 8 + p] = f2bf(r0);
        finalb[fb + 288 + h * 8 + p] = f2bf(r1);
        finalb[fb + 384 + h * 8 + p] = f2bf(r2);
        finalb[fb + 480 + h * 8 + p] = f2bf(nn);
    }
}

// ---------------------------------------------------------------------------
// LayerNorm(a + b) * scale + bias. Always writes bf16 to outb (stride 384);
// if outf != null also writes to d_out (stride 396) in flag-selected dtype.
// ---------------------------------------------------------------------------
__global__ __launch_bounds__(128) void k_ln(
    const bfu* __restrict__ a, const bfu* __restrict__ b,
    const bfu* __restrict__ sc, const bfu* __restrict__ bi,
    bfu* __restrict__ outb, void* __restrict__ outf, const u32* __restrict__ flags) {
    int r = blockIdx.x, t = threadIdx.x;
    __shared__ float red[2][2];
    float x[3];
    float s = 0.f, ss = 0.f;
#pragma unroll
    for (int i = 0; i < 3; ++i) {
        int c = t + i * 128;
        float v = bf2f(a[(size_t)r * 384 + c]) + bf2f(b[(size_t)r * 384 + c]);
        x[i] = v; s += v; ss += v * v;
    }
#pragma unroll
    for (int off = 1; off < 64; off <<= 1) { s += __shfl_xor(s, off); ss += __shfl_xor(ss, off); }
    int w = t >> 6;
    if ((t & 63) == 0) { red[w][0] = s; red[w][1] = ss; }
    __syncthreads();
    s = red[0][0] + red[1][0];
    ss = red[0][1] + red[1][1];
    float mu = s * (1.0f / 384.0f);
    float var = ss * (1.0f / 384.0f) - mu * mu;
    float rstd = rsqrtf(var + 1e-5f);
    bool f32o = flags[1] != 0u;
#pragma unroll
    for (int i = 0; i < 3; ++i) {
        int c = t + i * 128;
        float v = (x[i] - mu) * rstd * bf2f(sc[c]) + bf2f(bi[c]);
        outb[(size_t)r * 384 + c] = f2bf(v);
        if (outf) {
            if (f32o) ((float*)outf)[(size_t)r * 396 + c] = v;
            else      ((bfu*)outf)[(size_t)r * 396 + c] = f2bf(v);
        }
    }
}

// ---------------------------------------------------------------------------
// Quaternion rigid update. Reads act2 (bf16 ws), writes rot/trans to d_out.
// ---------------------------------------------------------------------------
__global__ __launch_bounds__(64) void k_quat(
    const bfu* __restrict__ act2,
    const bfu* __restrict__ rot, const bfu* __restrict__ trans,
    const bfu* __restrict__ wq, const bfu* __restrict__ bq,
    void* __restrict__ doutv, const u32* __restrict__ flags) {
    int r = blockIdx.x, t = threadIdx.x;
    float acc[6] = {};
    for (int i = 0; i < 6; ++i) {
        int k = t + i * 64;
        float xv = bf2f(act2[(size_t)r * 384 + k]);
#pragma unroll
        for (int o = 0; o < 6; ++o) acc[o] += xv * bf2f(wq[k * 6 + o]);
    }
#pragma unroll
    for (int o = 0; o < 6; ++o) {
#pragma unroll
        for (int off = 1; off < 64; off <<= 1) acc[o] += __shfl_xor(acc[o], off);
    }
    if (t == 0) {
        bool f32o = flags[1] != 0u;
        float v[6];
        for (int o = 0; o < 6; ++o) v[o] = acc[o] + bf2f(bq[o]);
        float w_ = 1.0f, x_ = v[0], y_ = v[1], z_ = v[2];
        float inv = rsqrtf(w_ * w_ + x_ * x_ + y_ * y_ + z_ * z_);
        w_ *= inv; x_ *= inv; y_ *= inv; z_ *= inv;
        float U[9];
        U[0] = 1 - 2 * (y_ * y_ + z_ * z_); U[1] = 2 * (x_ * y_ - w_ * z_); U[2] = 2 * (x_ * z_ + w_ * y_);
        U[3] = 2 * (x_ * y_ + w_ * z_); U[4] = 1 - 2 * (x_ * x_ + z_ * z_); U[5] = 2 * (y_ * z_ - w_ * x_);
        U[6] = 2 * (x_ * z_ - w_ * y_); U[7] = 2 * (y_ * z_ + w_ * x_); U[8] = 1 - 2 * (x_ * x_ + y_ * y_);
        float R[9];
        for (int i = 0; i < 9; ++i) R[i] = bf2f(rot[r * 9 + i]);
        for (int i = 0; i < 3; ++i)
            for (int j = 0; j < 3; ++j) {
                float sum = R[i * 3] * U[j] + R[i * 3 + 1] * U[3 + j] + R[i * 3 + 2] * U[6 + j];
                if (f32o) ((float*)doutv)[(size_t)r * 396 + 384 + i * 3 + j] = sum;
                else      ((bfu*)doutv)[(size_t)r * 396 + 384 + i * 3 + j] = f2bf(sum);
            }
        for (int i = 0; i < 3; ++i) {
            float sum = R[i * 3] * v[3] + R[i * 3 + 1] * v[4] + R[i * 3 + 2] * v[5] + bf2f(trans[r * 3 + i]);
            if (f32o) ((float*)doutv)[(size_t)r * 396 + 393 + i] = sum;
            else      ((bfu*)doutv)[(size_t)r * 396 + 393 + i] = f2bf(sum);
        }
    }
}

// ---------------------------------------------------------------------------
extern "C" void kernel_launch(void* const* d_in, const int* in_sizes, int n_in,
                              void* d_out, int out_size, void* d_ws, size_t ws_size,
                              hipStream_t stream) {
    (void)in_sizes; (void)n_in; (void)out_size; (void)ws_size;

    char* ws = (char*)d_ws;
    bfu* pl      = (bfu*)(ws + OFF_PL);
    float* fq    = (float*)(ws + OFF_FQ);
    float* gk    = (float*)(ws + OFF_GK);
    bfu* vsT     = (bfu*)(ws + OFF_VST);
    bfu* vgT     = (bfu*)(ws + OFF_VGT);
    float* logit = (float*)(ws + OFF_LOGITS);
    bfu* finalb  = (bfu*)(ws + OFF_FINAL);
    bfu* attnout = (bfu*)(ws + OFF_ATTNOUT);
    bfu* act     = (bfu*)(ws + OFF_ACT);
    bfu* x1      = (bfu*)(ws + OFF_X1);
    bfu* x2      = (bfu*)(ws + OFF_X2);
    bfu* act2    = x2;                       // reuse: x2 dead after gemm3
    bfu* wcat    = (bfu*)(ws + OFF_WCAT);
    bfu* bcat    = (bfu*)(ws + OFF_BCAT);
    bfu* conv    = (bfu*)(ws + OFF_CONV);
    u32* flags   = (u32*)(ws + OFF_FLAG);

    // conversion-area element offsets (order = d_in order minus inputs_2d)
    static const int offs[30] = {
        0, 294912, 295680, 302592, 304896, 360192, 360336, 415632, 415776,
        526368, 526656, 600384, 674112, 747840, 747852, 749388, 749400,
        1560408, 1560792, 1561176, 1561560, 1709016, 1709400, 1856856, 1857240,
        2004696, 2005080, 2005464, 2005848, 2008152
    };
    const bfu* c_in1d = conv + offs[0];
    const bfu* c_mask = conv + offs[1];
    const bfu* c_rot  = conv + offs[2];
    const bfu* c_trns = conv + offs[3];
    const bfu* c_wqp  = conv + offs[4];
    const bfu* c_bqp  = conv + offs[5];
    const bfu* c_wkp  = conv + offs[6];
    const bfu* c_bkp  = conv + offs[7];
    const bfu* c_wvp  = conv + offs[8];
    const bfu* c_bvp  = conv + offs[9];
    const bfu* c_wqs  = conv + offs[10];
    const bfu* c_wks  = conv + offs[11];
    const bfu* c_wvs  = conv + offs[12];
    const bfu* c_tpw  = conv + offs[13];
    const bfu* c_w2d  = conv + offs[14];
    const bfu* c_b2d  = conv + offs[15];
    const bfu* c_wout = conv + offs[16];
    const bfu* c_bout = conv + offs[17];
    const bfu* c_ln1s = conv + offs[18];
    const bfu* c_ln1b = conv + offs[19];
    const bfu* c_wt1  = conv + offs[20];
    const bfu* c_bt1  = conv + offs[21];
    const bfu* c_wt2  = conv + offs[22];
    const bfu* c_bt2  = conv + offs[23];
    const bfu* c_wt3  = conv + offs[24];
    const bfu* c_bt3  = conv + offs[25];
    const bfu* c_ln2s = conv + offs[26];
    const bfu* c_ln2b = conv + offs[27];
    const bfu* c_wqt  = conv + offs[28];
    const bfu* c_bqt  = conv + offs[29];

    P30 ps;
    ps.p[0] = d_in[0];
    for (int i = 1; i < 30; ++i) ps.p[i] = d_in[i + 1];
    const void* in2d = d_in[1];

    k_convert<<<(CONV_TOTAL + 255) / 256, 256, 0, stream>>>(ps, conv, flags);
    k_concat<<<1733, 256, 0, stream>>>(c_wqs, c_wks, c_wvs, c_wqp, c_bqp, c_wkp, c_bkp,
                                       c_wvp, c_bvp, wcat, bcat);
    k_gemm<0><<<dim3(36, 24), 256, 0, stream>>>(c_in1d, wcat, bcat, pl, 384, 1152);
    k_rigid<<<768, 64, 0, stream>>>(pl, c_rot, c_trns, c_tpw, c_b2d, fq, gk, vsT, vgT);
    k2a<<<dim3(12, 12, 12), 256, 0, stream>>>(fq, gk, logit);
    k2b<<<dim3(3, 768), 256, 0, stream>>>(in2d, c_w2d, c_mask, logit, flags);
    k3<<<768, 256, 0, stream>>>(logit, in2d, vsT, vgT, c_rot, c_trns, finalb, flags);
    k_gemm<0><<<dim3(12, 24), 256, 0, stream>>>(finalb, c_wout, c_bout, attnout, 2112, 384);
    k_ln<<<768, 128, 0, stream>>>(c_in1d, attnout, c_ln1s, c_ln1b, act, nullptr, flags);
    k_gemm<1><<<dim3(12, 24), 256, 0, stream>>>(act, c_wt1, c_bt1, x1, 384, 384);
    k_gemm<1><<<dim3(12, 24), 256, 0, stream>>>(x1, c_wt2, c_bt2, x2, 384, 384);
    k_gemm<0><<<dim3(12, 24), 256, 0, stream>>>(x2, c_wt3, c_bt3, x1, 384, 384);
    k_ln<<<768, 128, 0, stream>>>(act, x1, c_ln2s, c_ln2b, act2, d_out, flags);
    k_quat<<<768, 64, 0, stream>>>(act2, c_rot, c_trns, c_wqt, c_bqt, d_out, flags);
}